// Round 1
// baseline (159.398 us; speedup 1.0000x reference)
//
#include <hip/hip_runtime.h>
#include <cstdint>

// MXFP4 fake-quant linear: out = qdq(A) @ qdq(W)^T + bias
// Stage 1: quantize fp32 -> packed e2m1 + e8m0 scales (unchanged, verified).
// Stage 2: deep-pipelined fp4 GEMM, 256x256 tile, BK=128, 4-deep circular
// LDS buffers, counted vmcnt (never drained in main loop), setprio around
// MFMA clusters, 2-way-free XOR-swizzled LDS.

#define BM 256
#define BN 256
#define BK 128      // K elements per pipeline tile = one mfma k-step
#define NBUF 4

typedef float floatx4 __attribute__((ext_vector_type(4)));
typedef int intx8 __attribute__((ext_vector_type(8)));

#define GLOBAL_AS __attribute__((address_space(1)))
#define LDS_AS __attribute__((address_space(3)))

// ---------------- quantize fp32 -> packed fp4 + e8m0 scales ----------------
// Lane i loads contiguous float4; 8 consecutive lanes share one 1x32 block.

__device__ __forceinline__ int enc1(float x, float inv) {
    float q = x * inv;                         // inv = 2^-(e-2), exact
    q = fminf(fmaxf(q, -6.0f), 6.0f);
    int s = (int)(__float_as_uint(q) >> 31) << 3;
    float aq = fabsf(q);
    float ilsb = aq < 2.0f ? 2.0f : (aq < 4.0f ? 1.0f : 0.5f);
    float lsb  = aq < 2.0f ? 0.5f : (aq < 4.0f ? 1.0f : 2.0f);
    float ar = rintf(aq * ilsb) * lsb;         // RNE onto e2m1 grid (symmetric)
    int c;
    if (ar < 2.0f)      c = (int)(ar * 2.0f);  // 0,.5,1,1.5 -> 0..3
    else if (ar < 4.0f) c = 2 + (int)ar;       // 2,3 -> 4,5
    else                c = 4 + (int)(ar * 0.5f); // 4,6 -> 6,7
    return c | s;
}

__global__ void quant_mxfp4_v3(const float* __restrict__ A, uint8_t* __restrict__ Aq,
                               uint8_t* __restrict__ Asc,
                               const float* __restrict__ W, uint8_t* __restrict__ Wq,
                               uint8_t* __restrict__ Wsc,
                               long na4, long ntot4) {
    long t = (long)blockIdx.x * 256 + threadIdx.x;
    if (t >= ntot4) return;
    const float* src; uint8_t* dq; uint8_t* ds; long idx;
    if (t < na4) { src = A; dq = Aq; ds = Asc; idx = t; }
    else         { src = W; dq = Wq; ds = Wsc; idx = t - na4; }

    float4 f = ((const float4*)src)[idx];
    float amax = fmaxf(fmaxf(fabsf(f.x), fabsf(f.y)),
                       fmaxf(fabsf(f.z), fabsf(f.w)));
    amax = fmaxf(amax, __shfl_xor(amax, 1));
    amax = fmaxf(amax, __shfl_xor(amax, 2));
    amax = fmaxf(amax, __shfl_xor(amax, 4));

    int ebits = (int)((__float_as_uint(amax) >> 23) & 0xff);
    int sb;
    float inv;
    if (amax > 0.0f) {
        sb = ebits - 2; if (sb < 0) sb = 0;
        // inv = 2^(129 - ebits) = 2^(2 - e); exact power of two
        inv = __uint_as_float((unsigned)((256 - ebits) & 255) << 23);
    } else {
        sb = 127;              // scale 1.0, all-zero block
        inv = 0.0f;
    }

    int c0 = enc1(f.x, inv), c1 = enc1(f.y, inv);
    int c2 = enc1(f.z, inv), c3 = enc1(f.w, inv);
    // little-endian: elem 2i in low nibble of byte i
    ((unsigned short*)dq)[idx] =
        (unsigned short)(c0 | (c1 << 4) | (c2 << 8) | (c3 << 12));
    if ((idx & 7) == 0) ds[idx >> 3] = (uint8_t)sb;
}

// ---------- deep-pipelined fp4 GEMM: C[M,N] = (Aq,As) x (Wq,Ws)^T + bias ----
// 512 threads = 8 waves in a 2(M) x 4(N) grid; per-wave output 128x64.
// A-frag (16x16x128): row = lane&15, k-block = lane>>4 (32 elems = 16B).
// Scale operand: per-lane e8m0 byte of the lane's k-block, opsel 0.
// C/D: col(lane&15) = n-dim, row(quad*4+reg) = m-dim (verified convention).
//
// LDS swizzle: within each 64B row, 16B chunk slot c holds global chunk
// c ^ s(row), s(row) = (row ^ (row>>2)) & 3. Quarter-wave ds_read_b128 then
// lands 2 lanes/bank-group (free) instead of 8-way conflicts.
//
// Pipeline: 4 LDS buffers; while computing tile t, tile t+3 is being staged.
// Stage order per tile: P0 issues {A0,A1,scales}, P1 issues {B0,B1} = 5 vmem
// ops/tile. At end of tile t we wait vmcnt(10) (= tiles t+2,t+3 in flight,
// t+1 landed). No vmcnt(0) anywhere in the main loop.

__global__ __launch_bounds__(512, 2) void gemm_fp4_pipe(
        const uint8_t* __restrict__ Aq, const uint8_t* __restrict__ Asc,
        const uint8_t* __restrict__ Wq, const uint8_t* __restrict__ Wsc,
        const float* __restrict__ bias, float* __restrict__ C,
        int M, int N, int K) {
    __shared__ __align__(16) uint8_t sA[NBUF][BM * BK / 2];   // 4 x 16 KB
    __shared__ __align__(16) uint8_t sB[NBUF][BN * BK / 2];   // 4 x 16 KB
    __shared__ __align__(16) uint8_t sSA[NBUF][BM * 4];       // 4 x 1 KB
    __shared__ __align__(16) uint8_t sSB[NBUF][BN * 4];       // 4 x 1 KB

    const int tid = threadIdx.x;
    const int lane = tid & 63;
    const int w = tid >> 6;
    const int wr = w >> 2;           // 0..1 (M direction)
    const int wc = w & 3;            // 0..3 (N direction)
    const int row16 = lane & 15;
    const int quad = lane >> 4;      // k-block (32 elems) index
    const int shq = quad * 8;
    const int m0 = blockIdx.y * BM;
    const int n0 = blockIdx.x * BN;
    const int KB2 = K >> 1, KB32 = K >> 5;
    const int NT = K / BK;

    // per-thread constant fragment column offset (swizzle depends on row16 only)
    const int fragoff = (quad ^ ((row16 ^ (row16 >> 2)) & 3)) * 16;
    const int aRow = wr * 128 + row16;
    const int bRow = wc * 64 + row16;

    floatx4 acc[8][4];
#pragma unroll
    for (int i = 0; i < 8; i++)
#pragma unroll
        for (int j = 0; j < 4; j++) acc[i][j] = (floatx4){0.f, 0.f, 0.f, 0.f};

    auto stageA = [&](int tt) {   // A data (2 insts) + scales (1 inst)
        const int bb = tt & (NBUF - 1);
        const int kb = tt * (BK / 2);           // byte offset into packed K
#pragma unroll
        for (int it = 0; it < 2; ++it) {
            int idx = it * 512 + tid;           // 0..1023 16B chunks
            int row = idx >> 2, c = idx & 3;
            int g = c ^ ((row ^ (row >> 2)) & 3);   // pre-swizzled source col
            const uint8_t* src = Aq + (size_t)(m0 + row) * KB2 + kb + g * 16;
            __builtin_amdgcn_global_load_lds((GLOBAL_AS void*)src,
                (LDS_AS void*)(&sA[bb][idx * 16]), 16, 0, 0);
        }
        int r2 = tid & 255;
        if (tid < 256) {
            const uint8_t* src = Asc + (size_t)(m0 + r2) * KB32 + tt * 4;
            __builtin_amdgcn_global_load_lds((GLOBAL_AS void*)src,
                (LDS_AS void*)(&sSA[bb][r2 * 4]), 4, 0, 0);
        } else {
            const uint8_t* src = Wsc + (size_t)(n0 + r2) * KB32 + tt * 4;
            __builtin_amdgcn_global_load_lds((GLOBAL_AS void*)src,
                (LDS_AS void*)(&sSB[bb][r2 * 4]), 4, 0, 0);
        }
    };
    auto stageB = [&](int tt) {   // B data (2 insts)
        const int bb = tt & (NBUF - 1);
        const int kb = tt * (BK / 2);
#pragma unroll
        for (int it = 0; it < 2; ++it) {
            int idx = it * 512 + tid;
            int row = idx >> 2, c = idx & 3;
            int g = c ^ ((row ^ (row >> 2)) & 3);
            const uint8_t* src = Wq + (size_t)(n0 + row) * KB2 + kb + g * 16;
            __builtin_amdgcn_global_load_lds((GLOBAL_AS void*)src,
                (LDS_AS void*)(&sB[bb][idx * 16]), 16, 0, 0);
        }
    };
    auto fence = [] {
        __builtin_amdgcn_sched_barrier(0);
        __builtin_amdgcn_s_barrier();
    };

    // ---- prologue: stage tiles 0..2, wait for tile 0 ----
    stageA(0); stageB(0);
    if (NT > 1) { stageA(1); stageB(1); }
    if (NT > 2) { stageA(2); stageB(2); }
    if (NT > 2)      asm volatile("s_waitcnt vmcnt(10)" ::: "memory");
    else if (NT > 1) asm volatile("s_waitcnt vmcnt(5)" ::: "memory");
    else             asm volatile("s_waitcnt vmcnt(0)" ::: "memory");
    fence();

    for (int t = 0; t < NT; ++t) {
        const int p = t & (NBUF - 1);
        const uint8_t* pa = sA[p];
        const uint8_t* pb = sB[p];

        // ================= phase 0: mi 0..3 x ni 0..3 =================
        int4 bfr[4], afr[4];
        int sw32[4], sa32[4];
#pragma unroll
        for (int ni = 0; ni < 4; ++ni) {
            int r = bRow + ni * 16;
            bfr[ni] = *(const int4*)(pb + r * 64 + fragoff);
            sw32[ni] = *(const int*)(&sSB[p][r * 4]);
        }
#pragma unroll
        for (int mi = 0; mi < 4; ++mi) {
            int r = aRow + mi * 16;
            afr[mi] = *(const int4*)(pa + r * 64 + fragoff);
            sa32[mi] = *(const int*)(&sSA[p][r * 4]);
        }
        if (t + 3 < NT) stageA(t + 3);
        fence();

        int swb[4], sab[4];
#pragma unroll
        for (int ni = 0; ni < 4; ++ni) swb[ni] = (sw32[ni] >> shq) & 0xff;
#pragma unroll
        for (int mi = 0; mi < 4; ++mi) sab[mi] = (sa32[mi] >> shq) & 0xff;

        __builtin_amdgcn_s_setprio(1);
#pragma unroll
        for (int mi = 0; mi < 4; ++mi) {
            intx8 a8 = {afr[mi].x, afr[mi].y, afr[mi].z, afr[mi].w, 0, 0, 0, 0};
#pragma unroll
            for (int ni = 0; ni < 4; ++ni) {
                intx8 b8 = {bfr[ni].x, bfr[ni].y, bfr[ni].z, bfr[ni].w, 0, 0, 0, 0};
                acc[mi][ni] = __builtin_amdgcn_mfma_scale_f32_16x16x128_f8f6f4(
                    a8, b8, acc[mi][ni], 4, 4, 0, sab[mi], 0, swb[ni]);
            }
        }
        __builtin_amdgcn_s_setprio(0);
        fence();

        // ================= phase 1: mi 4..7 x ni 0..3 =================
#pragma unroll
        for (int mi = 0; mi < 4; ++mi) {
            int r = aRow + (mi + 4) * 16;
            afr[mi] = *(const int4*)(pa + r * 64 + fragoff);
            sa32[mi] = *(const int*)(&sSA[p][r * 4]);
        }
        if (t + 3 < NT) stageB(t + 3);
        fence();

#pragma unroll
        for (int mi = 0; mi < 4; ++mi) sab[mi] = (sa32[mi] >> shq) & 0xff;

        __builtin_amdgcn_s_setprio(1);
#pragma unroll
        for (int mi = 0; mi < 4; ++mi) {
            intx8 a8 = {afr[mi].x, afr[mi].y, afr[mi].z, afr[mi].w, 0, 0, 0, 0};
#pragma unroll
            for (int ni = 0; ni < 4; ++ni) {
                intx8 b8 = {bfr[ni].x, bfr[ni].y, bfr[ni].z, bfr[ni].w, 0, 0, 0, 0};
                acc[mi + 4][ni] = __builtin_amdgcn_mfma_scale_f32_16x16x128_f8f6f4(
                    a8, b8, acc[mi + 4][ni], 4, 4, 0, sab[mi], 0, swb[ni]);
            }
        }
        __builtin_amdgcn_s_setprio(0);

        // counted wait: ensure tile t+1 landed; keep t+2,t+3 in flight
        if (t < NT - 1) {
            int rem = NT - 2 - t;
            if (rem >= 2)      asm volatile("s_waitcnt vmcnt(10)" ::: "memory");
            else if (rem == 1) asm volatile("s_waitcnt vmcnt(5)" ::: "memory");
            else               asm volatile("s_waitcnt vmcnt(0)" ::: "memory");
        }
        fence();
    }

    // ---- epilogue: C/D col(lane&15)=n, row(quad*4+reg)=m ----
#pragma unroll
    for (int ni = 0; ni < 4; ++ni) {
        int n = n0 + wc * 64 + ni * 16 + row16;
        float bv = bias[n];
#pragma unroll
        for (int mi = 0; mi < 8; ++mi) {
            int mbase = m0 + wr * 128 + mi * 16 + quad * 4;
#pragma unroll
            for (int r = 0; r < 4; ++r) {
                C[(size_t)(mbase + r) * N + n] = acc[mi][ni][r] + bv;
            }
        }
    }
}

// ---------------- launch ----------------

extern "C" void kernel_launch(void* const* d_in, const int* in_sizes, int n_in,
                              void* d_out, int out_size, void* d_ws, size_t ws_size,
                              hipStream_t stream) {
    const float* inp  = (const float*)d_in[0];
    const float* wgt  = (const float*)d_in[1];
    const float* bias = (const float*)d_in[2];
    float* out = (float*)d_out;

    const int N = in_sizes[2];                 // 2048
    const int K = in_sizes[1] / N;             // 2048
    const long M = (long)in_sizes[0] / K;      // 8192

    uint8_t* Aq4 = (uint8_t*)d_ws;             // M*K/2
    uint8_t* Wq4 = Aq4 + (size_t)M * K / 2;    // N*K/2
    uint8_t* Asc = Wq4 + (size_t)N * K / 2;    // M*K/32
    uint8_t* Wsc = Asc + (size_t)M * K / 32;   // N*K/32

    long na4   = (long)M * K / 4;
    long ntot4 = na4 + (long)N * K / 4;
    quant_mxfp4_v3<<<dim3((ntot4 + 255) / 256), dim3(256), 0, stream>>>(
        inp, Aq4, Asc, wgt, Wq4, Wsc, na4, ntot4);

    dim3 grid(N / BN, (int)(M / BM));          // 8 x 32 = 256 WGs = 1/CU
    gemm_fp4_pipe<<<grid, dim3(512), 0, stream>>>(
        Aq4, Asc, Wq4, Wsc, bias, out, (int)M, N, K);
}